// Round 12
// baseline (1205.570 us; speedup 1.0000x reference)
//
#include <hip/hip_runtime.h>
#include <cfloat>
#include <cmath>

#define E      512
#define FOURE  2048
#define VT     50000
#define SLEN   128
#define TLEN   129            // decoder steps (targets + EOS)
#define NSTEPS 257
#define NB     64             // persistent LSTM blocks (64 <= 256 CUs -> co-resident)
#define NINBOX 32             // replicated inboxes; block bid polls inbox bid>>1
#define NCHUNK 98             // ceil(50000 / 512 cols-per-block)
#define TPAD   132

// ---- workspace layout (bytes); total 2,367,488 <= 2,597,572 proven (r1) ----
#define INBOX_OFF  0            // u64 inboxes[32][2][512] = 262144; memset 0 each call
#define GXE_OFF    262144       // 128*2048 f32 = 1048576 -> ends 1310720
#define PM_OFF     262144       //   alias GxE head (c1 runs after lstm): 98*132*4 = 51744
#define PS_OFF     317952       //   51744
#define TL_OFF     373760       //   129 f32 -> ends 374276
#define HALL_OFF   786432       //   alias GxE rows 64..96 (dead in decode): 264192 -> ends 1050624
#define GXD_OFF    1310720      // 129*2048 f32 = 1056768 -> ends 2367488

__device__ __forceinline__ float sigf(float x){ return 1.0f/(1.0f+__expf(-x)); }
__device__ __forceinline__ float tanhf_fast(float x){ return 2.f*sigf(2.f*x) - 1.f; }

// =================== A: Gx[t][r] = x_t @ W_ih^T + b_ih + b_hh ===================
__global__ __launch_bounds__(256) void gx_kernel(
    const int* __restrict__ src, const int* __restrict__ tgt,
    const float* __restrict__ Wx, const float* __restrict__ Wy,
    const float* __restrict__ encWih, const float* __restrict__ encBih, const float* __restrict__ encBhh,
    const float* __restrict__ decWih, const float* __restrict__ decBih, const float* __restrict__ decBhh,
    float* __restrict__ GxE, float* __restrict__ GxD)
{
  __shared__ float xs[8][E];
  const int tid  = threadIdx.x;
  const int tile = blockIdx.x;
  const bool is_dec = tile >= 16;
  const int t0 = is_dec ? (tile-16)*8 : tile*8;
  const int T  = is_dec ? TLEN : SLEN;

  for (int tt=0; tt<8; ++tt){
    int t = t0+tt;
    if (t < T){
      const float* xrow;
      if (is_dec) xrow = (t==0) ? (Wx + (size_t)1*E) : (Wy + (size_t)tgt[t-1]*E);
      else        xrow = Wx + (size_t)src[t]*E;
      xs[tt][tid]     = xrow[tid];
      xs[tt][tid+256] = xrow[tid+256];
    }
  }
  __syncthreads();

  const int r = blockIdx.y*256 + tid;
  const float* wrow = (is_dec ? decWih : encWih) + (size_t)r*E;
  const float  bias = is_dec ? (decBih[r]+decBhh[r]) : (encBih[r]+encBhh[r]);
  float acc[8];
  #pragma unroll
  for (int i=0;i<8;++i) acc[i]=0.f;

  for (int kc=0; kc<E; kc+=4){
    float4 w = *(const float4*)(wrow+kc);
    #pragma unroll
    for (int tt=0; tt<8; ++tt){
      float4 x = *(const float4*)&xs[tt][kc];
      acc[tt] += w.x*x.x + w.y*x.y + w.z*x.z + w.w*x.w;
    }
  }
  float* Gx = is_dec ? GxD : GxE;
  #pragma unroll
  for (int tt=0; tt<8; ++tt){
    int t = t0+tt;
    if (t < T) Gx[(size_t)t*FOURE + r] = bias + acc[tt];
  }
}

// =================== B: tagged ping-pong inbox dataflow LSTM (r10, unchanged) ===================
__device__ __forceinline__ void load_weights(
    const float* __restrict__ Whh, float* __restrict__ wldsw, int j, int lane)
{
  #pragma unroll
  for (int gg=0; gg<4; ++gg){
    const float* wr = Whh + (size_t)(gg*E + j)*E;
    float4 a = *(const float4*)(wr + 4*lane);
    float4 b = *(const float4*)(wr + 4*lane + 256);
    float* dst = wldsw + (size_t)gg*E + (lane&7)*64 + (lane>>3)*4;
    *(float4*)dst      = a;   // wlds[g][q*64+4p+r] = W_row[32p+4q+r]
    *(float4*)(dst+32) = b;
  }
}

__global__ __launch_bounds__(512, 1) void lstm_kernel(
    const float* __restrict__ GxE, const float* __restrict__ GxD,
    const float* __restrict__ encWhh, const float* __restrict__ decWhh,
    unsigned long long* __restrict__ inboxes, float* __restrict__ h_all)
{
  __shared__ float wlds[8][4][E];           // 64 KiB, wave-private slices
  __shared__ float hmir[2][576];            // padded h mirror
  const int tid  = threadIdx.x;
  const int lane = tid & 63, wave = tid >> 6, bid = blockIdx.x;
  const int g = lane >> 4, k = lane & 15;
  const int j = bid*8 + wave;
  const int row = g*E + j;
  const int slot  = wave*64 + lane;         // this thread's polled slot
  const int pslot = slot + 4*(slot>>5);     // padded LDS mirror index
  float* wldsw = &wlds[wave][0][0];
  const unsigned long long* myslot = inboxes + (size_t)(bid>>1)*1024 + slot;

  load_weights(encWhh, wldsw, j, lane);     // wave-private LDS region
  float cst = 0.f;

  for (int s=0; s<NSTEPS; ++s){
    if (s == SLEN){                         // enc -> dec boundary
      load_weights(decWhh, wldsw, j, lane); // wave-private region
      cst = 0.f;                            // reference resets cell state
    }
    const bool isdec = s >= SLEN;
    const int tloc = isdec ? (s - SLEN) : s;
    float gx = (isdec ? GxD : GxE)[(size_t)tloc*FOURE + row];

    float acc = 0.f;
    if (s > 0){
      const int buf = s & 1;
      // poll own slot of buffer buf until tag == s (1 u64 load per lane)
      unsigned long long hu;
      const unsigned long long* hp = myslot + (size_t)buf*512;
      for (int spin=0; spin<(1<<16); ++spin){
        hu = __hip_atomic_load(hp, __ATOMIC_RELAXED, __HIP_MEMORY_SCOPE_AGENT);
        if (__all((unsigned)(hu>>32) == (unsigned)s)) break;
        __builtin_amdgcn_s_sleep(1);
      }
      hmir[buf][pslot] = __uint_as_float((unsigned)hu);
      __syncthreads();                      // whole block: all 512 tags verified
      // dot: lane (g,k) needs h[32k+4i+r] = hmir[buf][36k+4i+r]
      const float* hb = &hmir[buf][36*k];
      #pragma unroll
      for (int i=0;i<8;++i){
        float4 h4 = *(const float4*)(hb + 4*i);
        float4 wv = *(const float4*)&wldsw[(size_t)g*E + i*64 + 4*k];
        acc += wv.x*h4.x + wv.y*h4.y + wv.z*h4.z + wv.w*h4.w;
      }
      // reduce over the 16 k-slice lanes (bits 0..3)
      acc += __shfl_xor(acc,1); acc += __shfl_xor(acc,2);
      acc += __shfl_xor(acc,4); acc += __shfl_xor(acc,8);
    }

    float gv = acc + gx;
    // all-gather the 4 gate values (bits 4..5)
    float x1 = __shfl_xor(gv,16);
    float x2 = __shfl_xor(gv,32);
    float x3 = __shfl_xor(x1,32);
    float gi = (g==0)?gv:(g==1)?x1:(g==2)?x2:x3;
    float gf = (g==0)?x1:(g==1)?gv:(g==2)?x3:x2;
    float gg = (g==0)?x2:(g==1)?x3:(g==2)?gv:x1;
    float go = (g==0)?x3:(g==1)?x2:(g==2)?x1:gv;
    cst = sigf(gf)*cst + sigf(gi)*tanhf_fast(gg);
    float hnew = sigf(go)*tanhf_fast(cst);

    // publish FIRST (critical path): {s+1,h} -> buffer (s+1)&1 of all 32 inboxes
    unsigned long long pk = ((unsigned long long)(unsigned)(s+1) << 32)
                          |  (unsigned long long)__float_as_uint(hnew);
    if (lane < NINBOX)
      __hip_atomic_store(inboxes + (size_t)lane*1024 + (size_t)((s+1)&1)*512 + j,
                         pk, __ATOMIC_RELAXED, __HIP_MEMORY_SCOPE_AGENT);
    if (isdec && lane==0) h_all[(size_t)tloc*E + j] = hnew;
  }
}

// =================== C1: logits GEMM + per-(t,chunk) softmax partials ===================
// LDS-free GEMM: h is wave-uniform -> scalar loads (s_load) feed v_fma's SGPR
// operand. W streamed per-lane from global (L3-resident). No LDS h staging,
// no ds_read bandwidth bound. 256 thr, 2 cols/thread, grid (98, 5).
__global__ __launch_bounds__(256) void c1_kernel(
    const float* __restrict__ h_all, const float* __restrict__ W, const float* __restrict__ bvec,
    const int* __restrict__ tgt, float* __restrict__ pm, float* __restrict__ ps, float* __restrict__ tl)
{
  __shared__ float red[8];
  const int tid  = threadIdx.x;
  const int wv   = tid >> 6, lane = tid & 63;
  const int chunk = blockIdx.x;
  const int t0    = blockIdx.y * 32;
  const int nt    = (t0 + 32 <= TLEN) ? 32 : (TLEN - t0);

  const int c0 = chunk*512 + tid;
  const int c1 = c0 + 256;
  const bool v0 = c0 < VT, v1 = c1 < VT;
  const float* w0 = W + (size_t)(v0 ? c0 : 0)*E;
  const float* w1 = W + (size_t)(v1 ? c1 : 0)*E;

  float acc0[32], acc1[32];
  #pragma unroll
  for (int i=0;i<32;++i){ acc0[i]=0.f; acc1[i]=0.f; }

  const float* hbase = h_all + (size_t)t0*E;   // uniform; tail rows read ws garbage, masked by act
  for (int kc=0; kc<E; kc+=4){
    float4 wa = *(const float4*)(w0+kc);
    float4 wb = *(const float4*)(w1+kc);
    #pragma unroll
    for (int tt=0; tt<32; ++tt){
      float4 h4 = *(const float4*)(hbase + (size_t)tt*E + kc);  // uniform -> s_load_dwordx4
      acc0[tt] += wa.x*h4.x + wa.y*h4.y + wa.z*h4.z + wa.w*h4.w;
      acc1[tt] += wb.x*h4.x + wb.y*h4.y + wb.z*h4.z + wb.w*h4.w;
    }
  }
  const float b0 = v0 ? bvec[c0] : 0.f;
  const float b1 = v1 ? bvec[c1] : 0.f;

  #pragma unroll
  for (int tt=0; tt<32; ++tt){
    const bool act = tt < nt;
    float x0 = v0 ? acc0[tt]+b0 : -FLT_MAX;
    float x1 = v1 ? acc1[tt]+b1 : -FLT_MAX;
    float mx = fmaxf(x0,x1);
    #pragma unroll
    for (int off=1; off<64; off<<=1) mx = fmaxf(mx, __shfl_xor(mx, off));
    if (lane==0) red[wv] = mx;
    __syncthreads();
    mx = fmaxf(fmaxf(red[0],red[1]), fmaxf(red[2],red[3]));
    float e = (v0 ? __expf(x0-mx) : 0.f) + (v1 ? __expf(x1-mx) : 0.f);
    #pragma unroll
    for (int off=1; off<64; off<<=1) e += __shfl_xor(e, off);
    if (lane==0) red[4+wv] = e;
    __syncthreads();
    float ssum = (red[4]+red[5]) + (red[6]+red[7]);
    if (act){
      int t = t0 + tt;
      if (tid==0){ pm[(size_t)chunk*TPAD + t] = mx; ps[(size_t)chunk*TPAD + t] = ssum; }
      int tok = (t < SLEN) ? tgt[t] : 1;
      if (v0 && c0==tok) tl[t] = x0;
      if (v1 && c1==tok) tl[t] = x1;
    }
    __syncthreads();
  }
}

// =================== C2: combine partials -> per-t loss -> sum ===================
__global__ __launch_bounds__(256) void c2_kernel(
    const float* __restrict__ pm, const float* __restrict__ ps, const float* __restrict__ tl,
    float* __restrict__ out)
{
  const int tid = threadIdx.x;
  float loss = 0.f;
  if (tid < TLEN){
    float m = -FLT_MAX, ssum = 0.f;
    for (int ch=0; ch<NCHUNK; ++ch){
      float mc = pm[(size_t)ch*TPAD + tid];
      float sc = ps[(size_t)ch*TPAD + tid];
      float nm = fmaxf(m, mc);
      ssum = ssum*__expf(m-nm) + sc*__expf(mc-nm);
      m = nm;
    }
    loss = (m + __logf(ssum)) - tl[tid];
  }
  __shared__ float red[4];
  #pragma unroll
  for (int off=1; off<64; off<<=1) loss += __shfl_xor(loss, off);
  if ((tid & 63)==0) red[tid>>6] = loss;
  __syncthreads();
  if (tid==0) out[0] = red[0]+red[1]+red[2]+red[3];
}

// =================== launch ===================
extern "C" void kernel_launch(void* const* d_in, const int* in_sizes, int n_in,
                              void* d_out, int out_size, void* d_ws, size_t ws_size,
                              hipStream_t stream)
{
  const int*   src    = (const int*)  d_in[0];
  const int*   tgt    = (const int*)  d_in[1];
  const float* Wx     = (const float*)d_in[2];
  const float* Wy     = (const float*)d_in[3];
  const float* encWih = (const float*)d_in[4];
  const float* encWhh = (const float*)d_in[5];
  const float* encBih = (const float*)d_in[6];
  const float* encBhh = (const float*)d_in[7];
  const float* decWih = (const float*)d_in[8];
  const float* decWhh = (const float*)d_in[9];
  const float* decBih = (const float*)d_in[10];
  const float* decBhh = (const float*)d_in[11];
  const float* Whr    = (const float*)d_in[12];
  const float* bhr    = (const float*)d_in[13];

  char* ws = (char*)d_ws;
  unsigned long long* inboxes = (unsigned long long*)(ws + INBOX_OFF);
  float* GxE    = (float*)(ws + GXE_OFF);
  float* GxD    = (float*)(ws + GXD_OFF);
  float* hall   = (float*)(ws + HALL_OFF);   // aliases GxE rows 64..96 (dead in decode)
  float* pm     = (float*)(ws + PM_OFF);     // aliases GxE head (c1 runs after lstm)
  float* ps     = (float*)(ws + PS_OFF);
  float* tl     = (float*)(ws + TL_OFF);

  // reset inbox tags (graph-replay safe: stale tags from prior call would race)
  hipMemsetAsync(ws + INBOX_OFF, 0, NINBOX*1024*8, stream);

  dim3 ggrid(33, 8);
  gx_kernel<<<ggrid, 256, 0, stream>>>(src, tgt, Wx, Wy,
      encWih, encBih, encBhh, decWih, decBih, decBhh, GxE, GxD);

  lstm_kernel<<<NB, 512, 0, stream>>>(GxE, GxD, encWhh, decWhh, inboxes, hall);

  dim3 cgrid(NCHUNK, 5);
  c1_kernel<<<cgrid, 256, 0, stream>>>(hall, Whr, bhr, tgt, pm, ps, tl);

  c2_kernel<<<1, 256, 0, stream>>>(pm, ps, tl, (float*)d_out);
}

// Round 13
// 1130.278 us; speedup vs baseline: 1.0666x; 1.0666x over previous
//
#include <hip/hip_runtime.h>
#include <cfloat>
#include <cmath>

#define E      512
#define FOURE  2048
#define VT     50000
#define SLEN   128
#define TLEN   129            // decoder steps (targets + EOS)
#define NSTEPS 257
#define NB     64             // persistent LSTM blocks (64 <= 256 CUs -> co-resident)
#define NINBOX 32             // replicated inboxes; block bid polls inbox bid>>1
#define NCHUNK 196            // ceil(50000 / 256 cols-per-block)
#define TPAD   132

// ---- workspace layout (bytes); total 2,367,488 <= 2,597,572 proven (r1) ----
#define INBOX_OFF  0            // u64 inboxes[32][2][512] = 262144; memset 0 each call
#define GXE_OFF    262144       // 128*2048 f32 = 1048576 -> ends 1310720
#define PM_OFF     262144       //   alias GxE head (c1 runs after lstm): 196*132*4 = 103488
#define PS_OFF     365632       //   103488
#define TL_OFF     469120       //   129 f32 -> ends 469636
#define HALL_OFF   786432       //   alias GxE rows 64..96 (dead in decode): 264192 -> ends 1050624
#define GXD_OFF    1310720      // 129*2048 f32 = 1056768 -> ends 2367488

__device__ __forceinline__ float sigf(float x){ return 1.0f/(1.0f+__expf(-x)); }
__device__ __forceinline__ float tanhf_fast(float x){ return 2.f*sigf(2.f*x) - 1.f; }

// =================== A: Gx[t][r] = x_t @ W_ih^T + b_ih + b_hh ===================
__global__ __launch_bounds__(256) void gx_kernel(
    const int* __restrict__ src, const int* __restrict__ tgt,
    const float* __restrict__ Wx, const float* __restrict__ Wy,
    const float* __restrict__ encWih, const float* __restrict__ encBih, const float* __restrict__ encBhh,
    const float* __restrict__ decWih, const float* __restrict__ decBih, const float* __restrict__ decBhh,
    float* __restrict__ GxE, float* __restrict__ GxD)
{
  __shared__ float xs[8][E];
  const int tid  = threadIdx.x;
  const int tile = blockIdx.x;
  const bool is_dec = tile >= 16;
  const int t0 = is_dec ? (tile-16)*8 : tile*8;
  const int T  = is_dec ? TLEN : SLEN;

  for (int tt=0; tt<8; ++tt){
    int t = t0+tt;
    if (t < T){
      const float* xrow;
      if (is_dec) xrow = (t==0) ? (Wx + (size_t)1*E) : (Wy + (size_t)tgt[t-1]*E);
      else        xrow = Wx + (size_t)src[t]*E;
      xs[tt][tid]     = xrow[tid];
      xs[tt][tid+256] = xrow[tid+256];
    }
  }
  __syncthreads();

  const int r = blockIdx.y*256 + tid;
  const float* wrow = (is_dec ? decWih : encWih) + (size_t)r*E;
  const float  bias = is_dec ? (decBih[r]+decBhh[r]) : (encBih[r]+encBhh[r]);
  float acc[8];
  #pragma unroll
  for (int i=0;i<8;++i) acc[i]=0.f;

  for (int kc=0; kc<E; kc+=4){
    float4 w = *(const float4*)(wrow+kc);
    #pragma unroll
    for (int tt=0; tt<8; ++tt){
      float4 x = *(const float4*)&xs[tt][kc];
      acc[tt] += w.x*x.x + w.y*x.y + w.z*x.z + w.w*x.w;
    }
  }
  float* Gx = is_dec ? GxD : GxE;
  #pragma unroll
  for (int tt=0; tt<8; ++tt){
    int t = t0+tt;
    if (t < T) Gx[(size_t)t*FOURE + r] = bias + acc[tt];
  }
}

// =================== B: tagged ping-pong inbox dataflow LSTM (r10, unchanged) ===================
__device__ __forceinline__ void load_weights(
    const float* __restrict__ Whh, float* __restrict__ wldsw, int j, int lane)
{
  #pragma unroll
  for (int gg=0; gg<4; ++gg){
    const float* wr = Whh + (size_t)(gg*E + j)*E;
    float4 a = *(const float4*)(wr + 4*lane);
    float4 b = *(const float4*)(wr + 4*lane + 256);
    float* dst = wldsw + (size_t)gg*E + (lane&7)*64 + (lane>>3)*4;
    *(float4*)dst      = a;   // wlds[g][q*64+4p+r] = W_row[32p+4q+r]
    *(float4*)(dst+32) = b;
  }
}

__global__ __launch_bounds__(512, 1) void lstm_kernel(
    const float* __restrict__ GxE, const float* __restrict__ GxD,
    const float* __restrict__ encWhh, const float* __restrict__ decWhh,
    unsigned long long* __restrict__ inboxes, float* __restrict__ h_all)
{
  __shared__ float wlds[8][4][E];           // 64 KiB, wave-private slices
  __shared__ float hmir[2][576];            // padded h mirror
  const int tid  = threadIdx.x;
  const int lane = tid & 63, wave = tid >> 6, bid = blockIdx.x;
  const int g = lane >> 4, k = lane & 15;
  const int j = bid*8 + wave;
  const int row = g*E + j;
  const int slot  = wave*64 + lane;         // this thread's polled slot
  const int pslot = slot + 4*(slot>>5);     // padded LDS mirror index
  float* wldsw = &wlds[wave][0][0];
  const unsigned long long* myslot = inboxes + (size_t)(bid>>1)*1024 + slot;

  load_weights(encWhh, wldsw, j, lane);     // wave-private LDS region
  float cst = 0.f;

  for (int s=0; s<NSTEPS; ++s){
    if (s == SLEN){                         // enc -> dec boundary
      load_weights(decWhh, wldsw, j, lane); // wave-private region
      cst = 0.f;                            // reference resets cell state
    }
    const bool isdec = s >= SLEN;
    const int tloc = isdec ? (s - SLEN) : s;
    float gx = (isdec ? GxD : GxE)[(size_t)tloc*FOURE + row];

    float acc = 0.f;
    if (s > 0){
      const int buf = s & 1;
      // poll own slot of buffer buf until tag == s (1 u64 load per lane)
      unsigned long long hu;
      const unsigned long long* hp = myslot + (size_t)buf*512;
      for (int spin=0; spin<(1<<16); ++spin){
        hu = __hip_atomic_load(hp, __ATOMIC_RELAXED, __HIP_MEMORY_SCOPE_AGENT);
        if (__all((unsigned)(hu>>32) == (unsigned)s)) break;
        __builtin_amdgcn_s_sleep(1);
      }
      hmir[buf][pslot] = __uint_as_float((unsigned)hu);
      __syncthreads();                      // whole block: all 512 tags verified
      // dot: lane (g,k) needs h[32k+4i+r] = hmir[buf][36k+4i+r]
      const float* hb = &hmir[buf][36*k];
      #pragma unroll
      for (int i=0;i<8;++i){
        float4 h4 = *(const float4*)(hb + 4*i);
        float4 wv = *(const float4*)&wldsw[(size_t)g*E + i*64 + 4*k];
        acc += wv.x*h4.x + wv.y*h4.y + wv.z*h4.z + wv.w*h4.w;
      }
      // reduce over the 16 k-slice lanes (bits 0..3)
      acc += __shfl_xor(acc,1); acc += __shfl_xor(acc,2);
      acc += __shfl_xor(acc,4); acc += __shfl_xor(acc,8);
    }

    float gv = acc + gx;
    // all-gather the 4 gate values (bits 4..5)
    float x1 = __shfl_xor(gv,16);
    float x2 = __shfl_xor(gv,32);
    float x3 = __shfl_xor(x1,32);
    float gi = (g==0)?gv:(g==1)?x1:(g==2)?x2:x3;
    float gf = (g==0)?x1:(g==1)?gv:(g==2)?x3:x2;
    float gg = (g==0)?x2:(g==1)?x3:(g==2)?gv:x1;
    float go = (g==0)?x3:(g==1)?x2:(g==2)?x1:gv;
    cst = sigf(gf)*cst + sigf(gi)*tanhf_fast(gg);
    float hnew = sigf(go)*tanhf_fast(cst);

    // publish FIRST (critical path): {s+1,h} -> buffer (s+1)&1 of all 32 inboxes
    unsigned long long pk = ((unsigned long long)(unsigned)(s+1) << 32)
                          |  (unsigned long long)__float_as_uint(hnew);
    if (lane < NINBOX)
      __hip_atomic_store(inboxes + (size_t)lane*1024 + (size_t)((s+1)&1)*512 + j,
                         pk, __ATOMIC_RELAXED, __HIP_MEMORY_SCOPE_AGENT);
    if (isdec && lane==0) h_all[(size_t)tloc*E + j] = hnew;
  }
}

// =================== C1: logits GEMM + per-(t,chunk) softmax partials ===================
// r10-proven variant: 128 threads, 256 cols/block, 32-row LDS h tile, grid (196, 5).
__global__ __launch_bounds__(128) void c1_kernel(
    const float* __restrict__ h_all, const float* __restrict__ W, const float* __restrict__ bvec,
    const int* __restrict__ tgt, float* __restrict__ pm, float* __restrict__ ps, float* __restrict__ tl)
{
  __shared__ float hst[32][E];               // exactly 64 KiB
  const int tid  = threadIdx.x;
  const int wv   = tid >> 6, lane = tid & 63;
  const int chunk = blockIdx.x;
  const int t0    = blockIdx.y * 32;
  const int nt    = (t0 + 32 <= TLEN) ? 32 : (TLEN - t0);

  for (int idx = tid; idx < nt*(E/4); idx += 128)
    ((float4*)&hst[0][0])[idx] = ((const float4*)(h_all + (size_t)t0*E))[idx];
  __syncthreads();

  const int c0 = chunk*256 + tid;
  const int c1 = c0 + 128;
  const bool v0 = c0 < VT, v1 = c1 < VT;
  const float* w0 = W + (size_t)(v0 ? c0 : 0)*E;
  const float* w1 = W + (size_t)(v1 ? c1 : 0)*E;

  float acc0[32], acc1[32];
  #pragma unroll
  for (int i=0;i<32;++i){ acc0[i]=0.f; acc1[i]=0.f; }

  for (int kc=0; kc<E; kc+=4){
    float4 wa = *(const float4*)(w0+kc);
    float4 wb = *(const float4*)(w1+kc);
    #pragma unroll
    for (int tt=0; tt<32; ++tt){
      float4 h4 = *(const float4*)&hst[tt][kc];  // uniform addr -> LDS broadcast
      acc0[tt] += wa.x*h4.x + wa.y*h4.y + wa.z*h4.z + wa.w*h4.w;
      acc1[tt] += wb.x*h4.x + wb.y*h4.y + wb.z*h4.z + wb.w*h4.w;
    }
  }
  const float b0 = v0 ? bvec[c0] : 0.f;
  const float b1 = v1 ? bvec[c1] : 0.f;

  __syncthreads();                           // hst dead; alias front as reduce scratch
  float* red = &hst[0][0];

  #pragma unroll
  for (int tt=0; tt<32; ++tt){
    const bool act = tt < nt;
    float x0 = v0 ? acc0[tt]+b0 : -FLT_MAX;
    float x1 = v1 ? acc1[tt]+b1 : -FLT_MAX;
    float mx = fmaxf(x0,x1);
    #pragma unroll
    for (int off=1; off<64; off<<=1) mx = fmaxf(mx, __shfl_xor(mx, off));
    if (lane==0) red[wv] = mx;
    __syncthreads();
    mx = fmaxf(red[0], red[1]);
    float e = (v0 ? __expf(x0-mx) : 0.f) + (v1 ? __expf(x1-mx) : 0.f);
    #pragma unroll
    for (int off=1; off<64; off<<=1) e += __shfl_xor(e, off);
    if (lane==0) red[2+wv] = e;
    __syncthreads();
    float ssum = red[2] + red[3];
    if (act){
      int t = t0 + tt;
      if (tid==0){ pm[(size_t)chunk*TPAD + t] = mx; ps[(size_t)chunk*TPAD + t] = ssum; }
      int tok = (t < SLEN) ? tgt[t] : 1;
      if (v0 && c0==tok) tl[t] = x0;
      if (v1 && c1==tok) tl[t] = x1;
    }
    __syncthreads();
  }
}

// =================== C2: combine partials -> per-t loss -> sum ===================
__global__ __launch_bounds__(256) void c2_kernel(
    const float* __restrict__ pm, const float* __restrict__ ps, const float* __restrict__ tl,
    float* __restrict__ out)
{
  const int tid = threadIdx.x;
  float loss = 0.f;
  if (tid < TLEN){
    float m = -FLT_MAX, ssum = 0.f;
    for (int ch=0; ch<NCHUNK; ++ch){
      float mc = pm[(size_t)ch*TPAD + tid];
      float sc = ps[(size_t)ch*TPAD + tid];
      float nm = fmaxf(m, mc);
      ssum = ssum*__expf(m-nm) + sc*__expf(mc-nm);
      m = nm;
    }
    loss = (m + __logf(ssum)) - tl[tid];
  }
  __shared__ float red[4];
  #pragma unroll
  for (int off=1; off<64; off<<=1) loss += __shfl_xor(loss, off);
  if ((tid & 63)==0) red[tid>>6] = loss;
  __syncthreads();
  if (tid==0) out[0] = red[0]+red[1]+red[2]+red[3];
}

// =================== launch ===================
extern "C" void kernel_launch(void* const* d_in, const int* in_sizes, int n_in,
                              void* d_out, int out_size, void* d_ws, size_t ws_size,
                              hipStream_t stream)
{
  const int*   src    = (const int*)  d_in[0];
  const int*   tgt    = (const int*)  d_in[1];
  const float* Wx     = (const float*)d_in[2];
  const float* Wy     = (const float*)d_in[3];
  const float* encWih = (const float*)d_in[4];
  const float* encWhh = (const float*)d_in[5];
  const float* encBih = (const float*)d_in[6];
  const float* encBhh = (const float*)d_in[7];
  const float* decWih = (const float*)d_in[8];
  const float* decWhh = (const float*)d_in[9];
  const float* decBih = (const float*)d_in[10];
  const float* decBhh = (const float*)d_in[11];
  const float* Whr    = (const float*)d_in[12];
  const float* bhr    = (const float*)d_in[13];

  char* ws = (char*)d_ws;
  unsigned long long* inboxes = (unsigned long long*)(ws + INBOX_OFF);
  float* GxE    = (float*)(ws + GXE_OFF);
  float* GxD    = (float*)(ws + GXD_OFF);
  float* hall   = (float*)(ws + HALL_OFF);   // aliases GxE rows 64..96 (dead in decode)
  float* pm     = (float*)(ws + PM_OFF);     // aliases GxE head (c1 runs after lstm)
  float* ps     = (float*)(ws + PS_OFF);
  float* tl     = (float*)(ws + TL_OFF);

  // reset inbox tags (graph-replay safe: stale tags from prior call would race)
  hipMemsetAsync(ws + INBOX_OFF, 0, NINBOX*1024*8, stream);

  dim3 ggrid(33, 8);
  gx_kernel<<<ggrid, 256, 0, stream>>>(src, tgt, Wx, Wy,
      encWih, encBih, encBhh, decWih, decBih, decBhh, GxE, GxD);

  lstm_kernel<<<NB, 512, 0, stream>>>(GxE, GxD, encWhh, decWhh, inboxes, hall);

  dim3 cgrid(NCHUNK, 5);
  c1_kernel<<<cgrid, 128, 0, stream>>>(hall, Whr, bhr, tgt, pm, ps, tl);

  c2_kernel<<<1, 256, 0, stream>>>(pm, ps, tl, (float*)d_out);
}

// Round 14
// 1101.605 us; speedup vs baseline: 1.0944x; 1.0260x over previous
//
#include <hip/hip_runtime.h>
#include <cfloat>
#include <cmath>

#define E      512
#define FOURE  2048
#define VT     50000
#define SLEN   128
#define TLEN   129            // decoder steps (targets + EOS)
#define NSTEPS 257
#define NBL    64             // lstm blocks (co-resident; proven r8/r10)
#define NC1    245            // c1 blocks: 49 per t-tile x 5 tiles (4 chunks each)
#define NGRID  309            // 64 + 245
#define NINBOX 32
#define NCHUNK 196
#define TPAD   132

// ---- workspace layout (bytes); total 2,371,616 <= 2,597,572 proven (r1) ----
#define INBOX_OFF  0            // u64 inboxes[32][2][512] = 262144; memset/call
#define GXE_OFF    262144       // 128*2048 f32 = 1048576 -> ends 1310720
#define PM_OFF     262144       //   alias GxE head; c1 writes only after prog-gate: 103488
#define PS_OFF     365632       //   103488
#define TL_OFF     469120       //   129 f32 -> ends 469636
#define HALL_OFF   786432       //   alias GxE rows 64..96 (dead in decode): u32[129][512]
#define GXD_OFF    1310720      // 129*2048 f32 = 1056768 -> ends 2367488
#define PROG_OFF   2367488      // u32 prog[258] at 16B stride = 4128; memset/call

__device__ __forceinline__ float sigf(float x){ return 1.0f/(1.0f+__expf(-x)); }
__device__ __forceinline__ float tanhf_fast(float x){ return 2.f*sigf(2.f*x) - 1.f; }

// =================== A: Gx[t][r] = x_t @ W_ih^T + b_ih + b_hh ===================
__global__ __launch_bounds__(256) void gx_kernel(
    const int* __restrict__ src, const int* __restrict__ tgt,
    const float* __restrict__ Wx, const float* __restrict__ Wy,
    const float* __restrict__ encWih, const float* __restrict__ encBih, const float* __restrict__ encBhh,
    const float* __restrict__ decWih, const float* __restrict__ decBih, const float* __restrict__ decBhh,
    float* __restrict__ GxE, float* __restrict__ GxD)
{
  __shared__ float xs[8][E];
  const int tid  = threadIdx.x;
  const int tile = blockIdx.x;
  const bool is_dec = tile >= 16;
  const int t0 = is_dec ? (tile-16)*8 : tile*8;
  const int T  = is_dec ? TLEN : SLEN;

  for (int tt=0; tt<8; ++tt){
    int t = t0+tt;
    if (t < T){
      const float* xrow;
      if (is_dec) xrow = (t==0) ? (Wx + (size_t)1*E) : (Wy + (size_t)tgt[t-1]*E);
      else        xrow = Wx + (size_t)src[t]*E;
      xs[tt][tid]     = xrow[tid];
      xs[tt][tid+256] = xrow[tid+256];
    }
  }
  __syncthreads();

  const int r = blockIdx.y*256 + tid;
  const float* wrow = (is_dec ? decWih : encWih) + (size_t)r*E;
  const float  bias = is_dec ? (decBih[r]+decBhh[r]) : (encBih[r]+encBhh[r]);
  float acc[8];
  #pragma unroll
  for (int i=0;i<8;++i) acc[i]=0.f;

  for (int kc=0; kc<E; kc+=4){
    float4 w = *(const float4*)(wrow+kc);
    #pragma unroll
    for (int tt=0; tt<8; ++tt){
      float4 x = *(const float4*)&xs[tt][kc];
      acc[tt] += w.x*x.x + w.y*x.y + w.z*x.z + w.w*x.w;
    }
  }
  float* Gx = is_dec ? GxD : GxE;
  #pragma unroll
  for (int tt=0; tt<8; ++tt){
    int t = t0+tt;
    if (t < T) Gx[(size_t)t*FOURE + r] = bias + acc[tt];
  }
}

// =================== MEGA: lstm (blocks 0..63) + gated c1 (blocks 64..308) ===================
// lstm: r10's proven tagged ping-pong inbox dataflow, verbatim, plus:
//   - h_all stores are agent-scope atomic u32 (MALL-visible for in-kernel readers)
//   - after each step-s __syncthreads (drains vmcnt -> this block's h_all stores
//     of step s-1 are MALL-acked), tid0 atomicAdd's prog[s]; epilogue adds prog[257].
//   prog[s]==64 proves ALL 512 waves passed step-s barrier -> all h_all rows
//   <= s-1-SLEN globally visible.
// c1: r10's proven body (4x 128-thread sub-blocks per 512-thr block), gated on
//   prog[160+32*ty] (ty<=3) / prog[257] (ty=4). Waits only on counters lstm
//   produces unconditionally -> deadlock-impossible; overlap is opportunistic.
__device__ __forceinline__ void load_weights_s(
    const float* __restrict__ Whh, float* __restrict__ wldsw, int j, int lane)
{
  #pragma unroll
  for (int gg=0; gg<4; ++gg){
    const float* wr = Whh + (size_t)(gg*E + j)*E;
    float4 a = *(const float4*)(wr + 4*lane);
    float4 b = *(const float4*)(wr + 4*lane + 256);
    float* dst = wldsw + (size_t)gg*E + (lane&7)*64 + (lane>>3)*4;
    *(float4*)dst      = a;   // wlds[g][q*64+4p+r] = W_row[32p+4q+r]
    *(float4*)(dst+32) = b;
  }
}

__global__ __launch_bounds__(512, 1) void mega_kernel(
    const float* __restrict__ GxE, const float* __restrict__ GxD,
    const float* __restrict__ encWhh, const float* __restrict__ decWhh,
    unsigned long long* __restrict__ inboxes, unsigned* __restrict__ h_all,
    unsigned* __restrict__ prog,
    const float* __restrict__ W, const float* __restrict__ bvec,
    const int* __restrict__ tgt,
    float* __restrict__ pm, float* __restrict__ ps, float* __restrict__ tl)
{
  __shared__ float smemf[17552];            // union: lstm 17536 f / c1 16400 f
  const int tid = threadIdx.x;

  if (blockIdx.x < NBL){
    // ---------------- LSTM part (r10 verbatim + prog/h_all changes) ----------------
    const int lane = tid & 63, wave = tid >> 6, bid = blockIdx.x;
    const int g = lane >> 4, k = lane & 15;
    const int j = bid*8 + wave;
    const int row = g*E + j;
    const int slot  = wave*64 + lane;
    const int pslot = slot + 4*(slot>>5);
    float* wldsw = smemf + wave*2048;       // wlds[8][4][512]
    float* hmir  = smemf + 16384;           // hmir[2][576]
    const unsigned long long* myslot = inboxes + (size_t)(bid>>1)*1024 + slot;

    load_weights_s(encWhh, wldsw, j, lane);
    float cst = 0.f;

    for (int s=0; s<NSTEPS; ++s){
      if (s == SLEN){
        load_weights_s(decWhh, wldsw, j, lane);
        cst = 0.f;                          // reference resets cell state
      }
      const bool isdec = s >= SLEN;
      const int tloc = isdec ? (s - SLEN) : s;
      float gx = (isdec ? GxD : GxE)[(size_t)tloc*FOURE + row];

      float acc = 0.f;
      if (s > 0){
        const int buf = s & 1;
        unsigned long long hu;
        const unsigned long long* hp = myslot + (size_t)buf*512;
        for (int spin=0; spin<(1<<16); ++spin){
          hu = __hip_atomic_load(hp, __ATOMIC_RELAXED, __HIP_MEMORY_SCOPE_AGENT);
          if (__all((unsigned)(hu>>32) == (unsigned)s)) break;
          __builtin_amdgcn_s_sleep(1);
        }
        hmir[buf*576 + pslot] = __uint_as_float((unsigned)hu);
        __syncthreads();                    // all 512 tags verified; vmcnt drained
        if (tid==0) atomicAdd(&prog[s*4], 1u);   // h_all rows <= s-1-SLEN acked
        const float* hb = hmir + buf*576 + 36*k;
        #pragma unroll
        for (int i=0;i<8;++i){
          float4 h4 = *(const float4*)(hb + 4*i);
          float4 wv = *(const float4*)&wldsw[(size_t)g*E + i*64 + 4*k];
          acc += wv.x*h4.x + wv.y*h4.y + wv.z*h4.z + wv.w*h4.w;
        }
        acc += __shfl_xor(acc,1); acc += __shfl_xor(acc,2);
        acc += __shfl_xor(acc,4); acc += __shfl_xor(acc,8);
      }

      float gv = acc + gx;
      float x1 = __shfl_xor(gv,16);
      float x2 = __shfl_xor(gv,32);
      float x3 = __shfl_xor(x1,32);
      float gi = (g==0)?gv:(g==1)?x1:(g==2)?x2:x3;
      float gf = (g==0)?x1:(g==1)?gv:(g==2)?x3:x2;
      float gg = (g==0)?x2:(g==1)?x3:(g==2)?gv:x1;
      float go = (g==0)?x3:(g==1)?x2:(g==2)?x1:gv;
      cst = sigf(gf)*cst + sigf(gi)*tanhf_fast(gg);
      float hnew = sigf(go)*tanhf_fast(cst);

      unsigned long long pk = ((unsigned long long)(unsigned)(s+1) << 32)
                            |  (unsigned long long)__float_as_uint(hnew);
      if (lane < NINBOX)
        __hip_atomic_store(inboxes + (size_t)lane*1024 + (size_t)((s+1)&1)*512 + j,
                           pk, __ATOMIC_RELAXED, __HIP_MEMORY_SCOPE_AGENT);
      if (isdec && lane==0)
        __hip_atomic_store(h_all + (size_t)tloc*E + j, __float_as_uint(hnew),
                           __ATOMIC_RELAXED, __HIP_MEMORY_SCOPE_AGENT);
    }
    // epilogue: prove final h_all row (tloc=128) visible
    __syncthreads();
    if (tid==0) atomicAdd(&prog[257*4], 1u);

  } else {
    // ---------------- C1 part (r10 body, 4 sub-blocks, prog-gated) ----------------
    const int bc   = blockIdx.x - NBL;
    const int ty   = bc / 49;               // t-tile 0..4
    const int sub  = tid >> 7;              // 0..3
    const int stid = tid & 127;
    const int chunk = (bc % 49)*4 + sub;    // 0..195
    const int wv   = stid >> 6, lane = tid & 63;
    const int t0   = ty * 32;
    const int nt   = (t0 + 32 <= TLEN) ? 32 : (TLEN - t0);
    float* hst  = smemf;                    // [32][512]
    float* redm = smemf + 16384;            // [4][2]
    float* reds = smemf + 16392;            // [4][2]

    // gate: wait until all decoder rows of this tile are provably visible
    const int gate_s = (ty < 4) ? (160 + 32*ty) : 257;
    if (tid == 0){
      for (int spin=0; spin<(1<<22); ++spin){
        if (__hip_atomic_load(&prog[gate_s*4], __ATOMIC_RELAXED, __HIP_MEMORY_SCOPE_AGENT)
            >= (unsigned)NBL) break;
        __builtin_amdgcn_s_sleep(16);
      }
    }
    __syncthreads();

    // stage h tile from MALL (agent loads; h_all was atomically stored)
    {
      unsigned long long* hst64 = (unsigned long long*)hst;
      const unsigned long long* hsrc = (const unsigned long long*)(h_all + (size_t)t0*E);
      for (int i=tid; i<nt*(E/2); i+=512)
        hst64[i] = __hip_atomic_load(hsrc+i, __ATOMIC_RELAXED, __HIP_MEMORY_SCOPE_AGENT);
    }
    __syncthreads();

    const int c0 = chunk*256 + stid;
    const int c1 = c0 + 128;
    const bool v0 = c0 < VT, v1 = c1 < VT;
    const float* w0 = W + (size_t)(v0 ? c0 : 0)*E;
    const float* w1 = W + (size_t)(v1 ? c1 : 0)*E;

    float acc0[32], acc1[32];
    #pragma unroll
    for (int i=0;i<32;++i){ acc0[i]=0.f; acc1[i]=0.f; }

    for (int kc=0; kc<E; kc+=4){
      float4 wa = *(const float4*)(w0+kc);
      float4 wb = *(const float4*)(w1+kc);
      #pragma unroll
      for (int tt=0; tt<32; ++tt){
        float4 h4 = *(const float4*)&hst[tt*E + kc];  // uniform -> LDS broadcast
        acc0[tt] += wa.x*h4.x + wa.y*h4.y + wa.z*h4.z + wa.w*h4.w;
        acc1[tt] += wb.x*h4.x + wb.y*h4.y + wb.z*h4.z + wb.w*h4.w;
      }
    }
    const float b0 = v0 ? bvec[c0] : 0.f;
    const float b1 = v1 ? bvec[c1] : 0.f;

    #pragma unroll
    for (int tt=0; tt<32; ++tt){
      const bool act = tt < nt;
      float x0 = v0 ? acc0[tt]+b0 : -FLT_MAX;
      float x1 = v1 ? acc1[tt]+b1 : -FLT_MAX;
      float mx = fmaxf(x0,x1);
      #pragma unroll
      for (int off=1; off<64; off<<=1) mx = fmaxf(mx, __shfl_xor(mx, off));
      if (lane==0) redm[sub*2+wv] = mx;
      __syncthreads();
      mx = fmaxf(redm[sub*2], redm[sub*2+1]);
      float e = (v0 ? __expf(x0-mx) : 0.f) + (v1 ? __expf(x1-mx) : 0.f);
      #pragma unroll
      for (int off=1; off<64; off<<=1) e += __shfl_xor(e, off);
      if (lane==0) reds[sub*2+wv] = e;
      __syncthreads();
      float ssum = reds[sub*2] + reds[sub*2+1];
      if (act){
        int t = t0 + tt;
        if (stid==0){ pm[(size_t)chunk*TPAD + t] = mx; ps[(size_t)chunk*TPAD + t] = ssum; }
        int tok = (t < SLEN) ? tgt[t] : 1;
        if (v0 && c0==tok) tl[t] = x0;
        if (v1 && c1==tok) tl[t] = x1;
      }
      __syncthreads();
    }
  }
}

// =================== C2: combine partials -> per-t loss -> sum ===================
__global__ __launch_bounds__(256) void c2_kernel(
    const float* __restrict__ pm, const float* __restrict__ ps, const float* __restrict__ tl,
    float* __restrict__ out)
{
  const int tid = threadIdx.x;
  float loss = 0.f;
  if (tid < TLEN){
    float m = -FLT_MAX, ssum = 0.f;
    for (int ch=0; ch<NCHUNK; ++ch){
      float mc = pm[(size_t)ch*TPAD + tid];
      float sc = ps[(size_t)ch*TPAD + tid];
      float nm = fmaxf(m, mc);
      ssum = ssum*__expf(m-nm) + sc*__expf(mc-nm);
      m = nm;
    }
    loss = (m + __logf(ssum)) - tl[tid];
  }
  __shared__ float red[4];
  #pragma unroll
  for (int off=1; off<64; off<<=1) loss += __shfl_xor(loss, off);
  if ((tid & 63)==0) red[tid>>6] = loss;
  __syncthreads();
  if (tid==0) out[0] = red[0]+red[1]+red[2]+red[3];
}

// =================== launch ===================
extern "C" void kernel_launch(void* const* d_in, const int* in_sizes, int n_in,
                              void* d_out, int out_size, void* d_ws, size_t ws_size,
                              hipStream_t stream)
{
  const int*   src    = (const int*)  d_in[0];
  const int*   tgt    = (const int*)  d_in[1];
  const float* Wx     = (const float*)d_in[2];
  const float* Wy     = (const float*)d_in[3];
  const float* encWih = (const float*)d_in[4];
  const float* encWhh = (const float*)d_in[5];
  const float* encBih = (const float*)d_in[6];
  const float* encBhh = (const float*)d_in[7];
  const float* decWih = (const float*)d_in[8];
  const float* decWhh = (const float*)d_in[9];
  const float* decBih = (const float*)d_in[10];
  const float* decBhh = (const float*)d_in[11];
  const float* Whr    = (const float*)d_in[12];
  const float* bhr    = (const float*)d_in[13];

  char* ws = (char*)d_ws;
  unsigned long long* inboxes = (unsigned long long*)(ws + INBOX_OFF);
  float* GxE     = (float*)(ws + GXE_OFF);
  float* GxD     = (float*)(ws + GXD_OFF);
  unsigned* hall = (unsigned*)(ws + HALL_OFF);  // aliases GxE rows 64..96 (dead in decode)
  unsigned* prog = (unsigned*)(ws + PROG_OFF);
  float* pm      = (float*)(ws + PM_OFF);       // aliases GxE head (prog-gated writes)
  float* ps      = (float*)(ws + PS_OFF);
  float* tl      = (float*)(ws + TL_OFF);

  // reset inbox tags + progress counters (graph-replay safe)
  hipMemsetAsync(ws + INBOX_OFF, 0, NINBOX*1024*8, stream);
  hipMemsetAsync(ws + PROG_OFF, 0, 258*16, stream);

  dim3 ggrid(33, 8);
  gx_kernel<<<ggrid, 256, 0, stream>>>(src, tgt, Wx, Wy,
      encWih, encBih, encBhh, decWih, decBih, decBhh, GxE, GxD);

  mega_kernel<<<NGRID, 512, 0, stream>>>(GxE, GxD, encWhh, decWhh,
      inboxes, hall, prog, Whr, bhr, tgt, pm, ps, tl);

  c2_kernel<<<1, 256, 0, stream>>>(pm, ps, tl, (float*)d_out);
}

// Round 15
// 1013.169 us; speedup vs baseline: 1.1899x; 1.0873x over previous
//
#include <hip/hip_runtime.h>
#include <cfloat>
#include <cmath>

#define E      512
#define FOURE  2048
#define VT     50000
#define SLEN   128
#define TLEN   129            // decoder steps (targets + EOS)
#define NSTEPS 257
#define NBL    64             // lstm blocks (co-resident; proven r8/r10/r14)
#define NGRID  554            // 64 lstm + 490 c1 (98 blocks x 5 tiles)
#define NINBOX 32
#define NCHUNK 392            // 128-col chunks
#define TPAD   132

// ---- workspace layout (bytes); total 2,371,616 <= 2,597,572 proven (r1) ----
#define INBOX_OFF  0            // u64 inboxes[32][2][512] = 262144; memset/call
#define GXE_OFF    262144       // 128*2048 f32 = 1048576 -> ends 1310720
#define PM_OFF     262144       //   alias GxE head (prog-gated writes): 392*132*4 = 206976
#define PS_OFF     469120       //   206976 -> ends 676096
#define TL_OFF     676096       //   129 f32 -> ends 676612 (< HALL_OFF, disjoint)
#define HALL_OFF   786432       //   alias GxE rows 64..96 (dead in decode): u32[129][512]
#define GXD_OFF    1310720      // 129*2048 f32 = 1056768 -> ends 2367488
#define PROG_OFF   2367488      // u32 prog[258] stride 16B = 4128; memset/call

__device__ __forceinline__ float sigf(float x){ return 1.0f/(1.0f+__expf(-x)); }
__device__ __forceinline__ float tanhf_fast(float x){ return 2.f*sigf(2.f*x) - 1.f; }

// =================== A: Gx[t][r] = x_t @ W_ih^T + b_ih + b_hh ===================
__global__ __launch_bounds__(256) void gx_kernel(
    const int* __restrict__ src, const int* __restrict__ tgt,
    const float* __restrict__ Wx, const float* __restrict__ Wy,
    const float* __restrict__ encWih, const float* __restrict__ encBih, const float* __restrict__ encBhh,
    const float* __restrict__ decWih, const float* __restrict__ decBih, const float* __restrict__ decBhh,
    float* __restrict__ GxE, float* __restrict__ GxD)
{
  __shared__ float xs[8][E];
  const int tid  = threadIdx.x;
  const int tile = blockIdx.x;
  const bool is_dec = tile >= 16;
  const int t0 = is_dec ? (tile-16)*8 : tile*8;
  const int T  = is_dec ? TLEN : SLEN;

  for (int tt=0; tt<8; ++tt){
    int t = t0+tt;
    if (t < T){
      const float* xrow;
      if (is_dec) xrow = (t==0) ? (Wx + (size_t)1*E) : (Wy + (size_t)tgt[t-1]*E);
      else        xrow = Wx + (size_t)src[t]*E;
      xs[tt][tid]     = xrow[tid];
      xs[tt][tid+256] = xrow[tid+256];
    }
  }
  __syncthreads();

  const int r = blockIdx.y*256 + tid;
  const float* wrow = (is_dec ? decWih : encWih) + (size_t)r*E;
  const float  bias = is_dec ? (decBih[r]+decBhh[r]) : (encBih[r]+encBhh[r]);
  float acc[8];
  #pragma unroll
  for (int i=0;i<8;++i) acc[i]=0.f;

  for (int kc=0; kc<E; kc+=4){
    float4 w = *(const float4*)(wrow+kc);
    #pragma unroll
    for (int tt=0; tt<8; ++tt){
      float4 x = *(const float4*)&xs[tt][kc];
      acc[tt] += w.x*x.x + w.y*x.y + w.z*x.z + w.w*x.w;
    }
  }
  float* Gx = is_dec ? GxD : GxE;
  #pragma unroll
  for (int tt=0; tt<8; ++tt){
    int t = t0+tt;
    if (t < T) Gx[(size_t)t*FOURE + r] = bias + acc[tt];
  }
}

// =================== MEGA: lstm (blocks 0..63) + gated kc-split c1 ===================
__device__ __forceinline__ void load_weights_s(
    const float* __restrict__ Whh, float* __restrict__ wldsw, int j, int lane)
{
  #pragma unroll
  for (int gg=0; gg<4; ++gg){
    const float* wr = Whh + (size_t)(gg*E + j)*E;
    float4 a = *(const float4*)(wr + 4*lane);
    float4 b = *(const float4*)(wr + 4*lane + 256);
    float* dst = wldsw + (size_t)gg*E + (lane&7)*64 + (lane>>3)*4;
    *(float4*)dst      = a;   // wlds[g][q*64+4p+r] = W_row[32p+4q+r]
    *(float4*)(dst+32) = b;
  }
}

__global__ __launch_bounds__(512, 1) void mega_kernel(
    const float* __restrict__ GxE, const float* __restrict__ GxD,
    const float* __restrict__ encWhh, const float* __restrict__ decWhh,
    unsigned long long* __restrict__ inboxes, unsigned* __restrict__ h_all,
    unsigned* __restrict__ prog,
    const float* __restrict__ W, const float* __restrict__ bvec,
    const int* __restrict__ tgt,
    float* __restrict__ pm, float* __restrict__ ps, float* __restrict__ tl)
{
  __shared__ float smemf[17552];            // lstm: wlds 16384 + hmir 1152 | c1: hst 16384 (+reduce reuse)
  const int tid = threadIdx.x;

  if (blockIdx.x < NBL){
    // ---------------- LSTM part (r14 verbatim) ----------------
    const int lane = tid & 63, wave = tid >> 6, bid = blockIdx.x;
    const int g = lane >> 4, k = lane & 15;
    const int j = bid*8 + wave;
    const int row = g*E + j;
    const int slot  = wave*64 + lane;
    const int pslot = slot + 4*(slot>>5);
    float* wldsw = smemf + wave*2048;       // wlds[8][4][512]
    float* hmir  = smemf + 16384;           // hmir[2][576]
    const unsigned long long* myslot = inboxes + (size_t)(bid>>1)*1024 + slot;

    load_weights_s(encWhh, wldsw, j, lane);
    float cst = 0.f;

    for (int s=0; s<NSTEPS; ++s){
      if (s == SLEN){
        load_weights_s(decWhh, wldsw, j, lane);
        cst = 0.f;                          // reference resets cell state
      }
      const bool isdec = s >= SLEN;
      const int tloc = isdec ? (s - SLEN) : s;
      float gx = (isdec ? GxD : GxE)[(size_t)tloc*FOURE + row];

      float acc = 0.f;
      if (s > 0){
        const int buf = s & 1;
        unsigned long long hu;
        const unsigned long long* hp = myslot + (size_t)buf*512;
        for (int spin=0; spin<(1<<16); ++spin){
          hu = __hip_atomic_load(hp, __ATOMIC_RELAXED, __HIP_MEMORY_SCOPE_AGENT);
          if (__all((unsigned)(hu>>32) == (unsigned)s)) break;
          __builtin_amdgcn_s_sleep(1);
        }
        hmir[buf*576 + pslot] = __uint_as_float((unsigned)hu);
        __syncthreads();                    // all 512 tags verified; vmcnt drained
        if (tid==0) atomicAdd(&prog[s*4], 1u);   // h_all rows <= s-1-SLEN acked
        const float* hb = hmir + buf*576 + 36*k;
        #pragma unroll
        for (int i=0;i<8;++i){
          float4 h4 = *(const float4*)(hb + 4*i);
          float4 wv = *(const float4*)&wldsw[(size_t)g*E + i*64 + 4*k];
          acc += wv.x*h4.x + wv.y*h4.y + wv.z*h4.z + wv.w*h4.w;
        }
        acc += __shfl_xor(acc,1); acc += __shfl_xor(acc,2);
        acc += __shfl_xor(acc,4); acc += __shfl_xor(acc,8);
      }

      float gv = acc + gx;
      float x1 = __shfl_xor(gv,16);
      float x2 = __shfl_xor(gv,32);
      float x3 = __shfl_xor(x1,32);
      float gi = (g==0)?gv:(g==1)?x1:(g==2)?x2:x3;
      float gf = (g==0)?x1:(g==1)?gv:(g==2)?x3:x2;
      float gg = (g==0)?x2:(g==1)?x3:(g==2)?gv:x1;
      float go = (g==0)?x3:(g==1)?x2:(g==2)?x1:gv;
      cst = sigf(gf)*cst + sigf(gi)*tanhf_fast(gg);
      float hnew = sigf(go)*tanhf_fast(cst);

      unsigned long long pk = ((unsigned long long)(unsigned)(s+1) << 32)
                            |  (unsigned long long)__float_as_uint(hnew);
      if (lane < NINBOX)
        __hip_atomic_store(inboxes + (size_t)lane*1024 + (size_t)((s+1)&1)*512 + j,
                           pk, __ATOMIC_RELAXED, __HIP_MEMORY_SCOPE_AGENT);
      if (isdec && lane==0)
        __hip_atomic_store(h_all + (size_t)tloc*E + j, __float_as_uint(hnew),
                           __ATOMIC_RELAXED, __HIP_MEMORY_SCOPE_AGENT);
    }
    __syncthreads();
    if (tid==0) atomicAdd(&prog[257*4], 1u);   // final h_all row visible

  } else {
    // ---------------- C1 part: kc-split sub-blocks, prog-gated ----------------
    // 490 blocks: ty = bc/98 (t-tile), 4 subs/block, chunk = (bc%98)*4+sub in [0,392).
    // Sub = 128 thr = 2 waves over the SAME 128 cols; wave wv accumulates kc-half
    // [wv*256, wv*256+256). Reduce via LDS (dead hst, stride 65 -> conflict-free),
    // then wave0-only softmax (single-wave cols -> pure shfl, no barriers).
    const int bc   = blockIdx.x - NBL;
    const int ty   = bc / 98;               // t-tile 0..4
    const int sub  = tid >> 7;              // 0..3
    const int stid = tid & 127;
    const int wv   = stid >> 6;             // kc-half
    const int lane = tid & 63;
    const int chunk = (bc % 98)*4 + sub;    // 0..391
    const int t0   = ty * 32;
    const int nt   = (t0 + 32 <= TLEN) ? 32 : (TLEN - t0);
    float* hst  = smemf;                    // [32][512]; reduce area reuses this

    // gate: all decoder rows of this tile provably visible
    const int gate_s = (ty < 4) ? (160 + 32*ty) : 257;
    if (tid == 0){
      for (int spin=0; spin<(1<<22); ++spin){
        if (__hip_atomic_load(&prog[gate_s*4], __ATOMIC_RELAXED, __HIP_MEMORY_SCOPE_AGENT)
            >= (unsigned)NBL) break;
        __builtin_amdgcn_s_sleep(16);
      }
    }
    __syncthreads();

    // stage h tile (agent loads; h_all stored atomically)
    {
      unsigned long long* hst64 = (unsigned long long*)hst;
      const unsigned long long* hsrc = (const unsigned long long*)(h_all + (size_t)t0*E);
      for (int i=tid; i<nt*(E/2); i+=512)
        hst64[i] = __hip_atomic_load(hsrc+i, __ATOMIC_RELAXED, __HIP_MEMORY_SCOPE_AGENT);
    }
    __syncthreads();

    const int c0 = chunk*128 + lane;        // wave0 & wave1: same cols
    const int c1 = c0 + 64;
    const bool v0 = c0 < VT, v1 = c1 < VT;
    const float* w0 = W + (size_t)(v0 ? c0 : 0)*E;
    const float* w1 = W + (size_t)(v1 ? c1 : 0)*E;

    float acc0[32], acc1[32];
    #pragma unroll
    for (int i=0;i<32;++i){ acc0[i]=0.f; acc1[i]=0.f; }

    const int kc0 = wv*256;                 // this wave's kc half
    for (int kc=kc0; kc<kc0+256; kc+=4){
      float4 wa = *(const float4*)(w0+kc);
      float4 wb = *(const float4*)(w1+kc);
      #pragma unroll
      for (int tt=0; tt<32; ++tt){
        float4 h4 = *(const float4*)&hst[tt*E + kc];  // uniform -> LDS broadcast
        acc0[tt] += wa.x*h4.x + wa.y*h4.y + wa.z*h4.z + wa.w*h4.w;
        acc1[tt] += wb.x*h4.x + wb.y*h4.y + wb.z*h4.z + wb.w*h4.w;
      }
    }

    // reduce kc-halves: wave1 -> LDS (reuses dead hst; stride 65 = conflict-free)
    __syncthreads();                        // all subs done with hst reads
    float* ldsR = smemf + sub*4160;
    if (wv == 1){
      #pragma unroll
      for (int i=0;i<32;++i){
        ldsR[lane*65 + i]      = acc0[i];
        ldsR[lane*65 + 32 + i] = acc1[i];
      }
    }
    __syncthreads();
    if (wv == 0){
      #pragma unroll
      for (int i=0;i<32;++i){
        acc0[i] += ldsR[lane*65 + i];
        acc1[i] += ldsR[lane*65 + 32 + i];
      }
      const float b0 = v0 ? bvec[c0] : 0.f;
      const float b1 = v1 ? bvec[c1] : 0.f;

      #pragma unroll
      for (int tt=0; tt<32; ++tt){
        if (tt < nt){
          float x0 = v0 ? acc0[tt]+b0 : -FLT_MAX;
          float x1 = v1 ? acc1[tt]+b1 : -FLT_MAX;
          float mx = fmaxf(x0,x1);
          #pragma unroll
          for (int off=1; off<64; off<<=1) mx = fmaxf(mx, __shfl_xor(mx, off));
          float e = (v0 ? __expf(x0-mx) : 0.f) + (v1 ? __expf(x1-mx) : 0.f);
          #pragma unroll
          for (int off=1; off<64; off<<=1) e += __shfl_xor(e, off);
          int t = t0 + tt;
          if (lane==0){ pm[(size_t)chunk*TPAD + t] = mx; ps[(size_t)chunk*TPAD + t] = e; }
          int tok = (t < SLEN) ? tgt[t] : 1;
          if (v0 && c0==tok) tl[t] = x0;
          if (v1 && c1==tok) tl[t] = x1;
        }
      }
    }
  }
}

// =================== C2: combine partials -> per-t loss -> sum ===================
__global__ __launch_bounds__(256) void c2_kernel(
    const float* __restrict__ pm, const float* __restrict__ ps, const float* __restrict__ tl,
    float* __restrict__ out)
{
  const int tid = threadIdx.x;
  float loss = 0.f;
  if (tid < TLEN){
    float m = -FLT_MAX, ssum = 0.f;
    for (int ch=0; ch<NCHUNK; ++ch){
      float mc = pm[(size_t)ch*TPAD + tid];
      float sc = ps[(size_t)ch*TPAD + tid];
      float nm = fmaxf(m, mc);
      ssum = ssum*__expf(m-nm) + sc*__expf(mc-nm);
      m = nm;
    }
    loss = (m + __logf(ssum)) - tl[tid];
  }
  __shared__ float red[4];
  #pragma unroll
  for (int off=1; off<64; off<<=1) loss += __shfl_xor(loss, off);
  if ((tid & 63)==0) red[tid>>6] = loss;
  __syncthreads();
  if (tid==0) out[0] = red[0]+red[1]+red[2]+red[3];
}

// =================== launch ===================
extern "C" void kernel_launch(void* const* d_in, const int* in_sizes, int n_in,
                              void* d_out, int out_size, void* d_ws, size_t ws_size,
                              hipStream_t stream)
{
  const int*   src    = (const int*)  d_in[0];
  const int*   tgt    = (const int*)  d_in[1];
  const float* Wx     = (const float*)d_in[2];
  const float* Wy     = (const float*)d_in[3];
  const float* encWih = (const float*)d_in[4];
  const float* encWhh = (const float*)d_in[5];
  const float* encBih = (const float*)d_in[6];
  const float* encBhh = (const float*)d_in[7];
  const float* decWih = (const float*)d_in[8];
  const float* decWhh = (const float*)d_in[9];
  const float* decBih = (const float*)d_in[10];
  const float* decBhh = (const float*)d_in[11];
  const float* Whr    = (const float*)d_in[12];
  const float* bhr    = (const float*)d_in[13];

  char* ws = (char*)d_ws;
  unsigned long long* inboxes = (unsigned long long*)(ws + INBOX_OFF);
  float* GxE     = (float*)(ws + GXE_OFF);
  float* GxD     = (float*)(ws + GXD_OFF);
  unsigned* hall = (unsigned*)(ws + HALL_OFF);  // aliases GxE rows 64..96 (dead in decode)
  unsigned* prog = (unsigned*)(ws + PROG_OFF);
  float* pm      = (float*)(ws + PM_OFF);       // aliases GxE head (prog-gated writes)
  float* ps      = (float*)(ws + PS_OFF);
  float* tl      = (float*)(ws + TL_OFF);

  hipMemsetAsync(ws + INBOX_OFF, 0, NINBOX*1024*8, stream);
  hipMemsetAsync(ws + PROG_OFF, 0, 258*16, stream);

  dim3 ggrid(33, 8);
  gx_kernel<<<ggrid, 256, 0, stream>>>(src, tgt, Wx, Wy,
      encWih, encBih, encBhh, decWih, decBih, decBhh, GxE, GxD);

  mega_kernel<<<NGRID, 512, 0, stream>>>(GxE, GxD, encWhh, decWhh,
      inboxes, hall, prog, Whr, bhr, tgt, pm, ps, tl);

  c2_kernel<<<1, 256, 0, stream>>>(pm, ps, tl, (float*)d_out);
}